// Round 11
// baseline (1289.852 us; speedup 1.0000x reference)
//
#include <hip/hip_runtime.h>
#include <hip/hip_bf16.h>

#define DEV __device__ __forceinline__

typedef __attribute__((ext_vector_type(8))) short bhalf8;
typedef __attribute__((ext_vector_type(4))) float floatx4;
typedef unsigned short ushort_t;

constexpr int NB = 16384;   // batch
constexpr int NV = 4096;    // visible
constexpr int NH = 1024;    // hidden
constexpr float MOM = 0.5f;
constexpr float WD  = 1e-4f;
constexpr float LRB = 1e-3f / 16384.0f;

// Tile 256(M) x 128(N) x 32(K); 4 waves, each owns 128x64 (8x4 fragments).
// 3 LDS buffers of 24KB (A 16KB + B 8KB) = 72KB -> 2 blocks/CU.
constexpr int BUF_SHORTS = 12288;            // per buffer
constexpr int LDS_SHORTS = 3 * BUF_SHORTS;   // 36864 shorts = 72KB
constexpr size_t LDS_BYTES = LDS_SHORTS * 2 + 1024 + 64;  // + colp(256f) + ered
// epilogue repack region: [256][132] shorts = 67584 B < 73728 B  (fits)

DEV unsigned short f2bf(float f) {
  unsigned u = __builtin_bit_cast(unsigned, f);
  u += 0x7FFFu + ((u >> 16) & 1u);      // RNE
  return (unsigned short)(u >> 16);
}
DEV float bf2f(unsigned short u) {
  unsigned x = ((unsigned)u) << 16;
  return __builtin_bit_cast(float, x);
}
DEV float sigm(float x) { return 1.0f / (1.0f + __expf(-x)); }

DEV void gl16(const ushort_t* g, ushort_t* l) {
  __builtin_amdgcn_global_load_lds(
      (const __attribute__((address_space(1))) void*)g,
      (__attribute__((address_space(3))) void*)l,
      16, 0, 0);
}

// ================= conflict-free 64x64 bf16 transpose machinery =================
struct TransLds { unsigned U[64 * 33]; };

DEV void trans_store(TransLds& T, const bhalf8& ra, const bhalf8& rb, int a, int e) {
  const unsigned* ua = (const unsigned*)&ra;
  const unsigned* ub = (const unsigned*)&rb;
#pragma unroll
  for (int c2 = 0; c2 < 4; ++c2) {
    unsigned lo = __builtin_amdgcn_perm(ub[c2], ua[c2], 0x05040100u);  // A.lo | B.lo<<16
    unsigned hi = __builtin_amdgcn_perm(ub[c2], ua[c2], 0x07060302u);  // A.hi | B.hi<<16
    T.U[(e * 8 + 2 * c2) * 33 + a] = lo;
    T.U[(e * 8 + 2 * c2 + 1) * 33 + a] = hi;
  }
}

DEV void trans_flush(const TransLds& T, ushort_t* __restrict__ oT,
                     int c0, int r0, int R, int tid) {
  const int g = tid >> 2, f = tid & 3;
  unsigned w[8];
#pragma unroll
  for (int i = 0; i < 8; ++i) w[i] = T.U[g * 33 + f * 8 + i];
  ushort_t* dst = oT + (size_t)(c0 + g) * R + r0 + f * 16;
  *(bhalf8*)dst = *(const bhalf8*)&w[0];
  *(bhalf8*)(dst + 8) = *(const bhalf8*)&w[4];
}

// ---------- f32 [R][C] -> bf16 [R][C] and bf16 [C][R]; non-atomic col partials ----------
__global__ void prep_cvt_t(const float* __restrict__ in,
                           ushort_t* __restrict__ obf,
                           ushort_t* __restrict__ oT, int R, int C,
                           float* __restrict__ pin) {
  __shared__ TransLds T;
  __shared__ float wp[4][64];
  const int c0 = blockIdx.x * 64, r0 = blockIdx.y * 64;
  const int tid = threadIdx.x;
  const int a = tid >> 3, e = tid & 7;
  const int rA = r0 + 2 * a, cB = c0 + e * 8;

  const float* pA = in + (size_t)rA * C + cB;
  const float* pB = pA + C;
  floatx4 a0 = *(const floatx4*)pA, a1 = *(const floatx4*)(pA + 4);
  floatx4 b0 = *(const floatx4*)pB, b1 = *(const floatx4*)(pB + 4);

  bhalf8 ra, rb;
#pragma unroll
  for (int j = 0; j < 4; ++j) {
    ra[j] = (short)f2bf(a0[j]); ra[4 + j] = (short)f2bf(a1[j]);
    rb[j] = (short)f2bf(b0[j]); rb[4 + j] = (short)f2bf(b1[j]);
  }
  *(bhalf8*)(obf + (size_t)rA * C + cB) = ra;
  *(bhalf8*)(obf + (size_t)(rA + 1) * C + cB) = rb;

  if (pin) {
    float ps[8];
#pragma unroll
    for (int j = 0; j < 4; ++j) { ps[j] = a0[j] + b0[j]; ps[4 + j] = a1[j] + b1[j]; }
#pragma unroll
    for (int j = 0; j < 8; ++j) {
      ps[j] += __shfl_xor(ps[j], 8);
      ps[j] += __shfl_xor(ps[j], 16);
      ps[j] += __shfl_xor(ps[j], 32);
    }
    const int wid = tid >> 6, lane = tid & 63;
    if (lane < 8) {
#pragma unroll
      for (int j = 0; j < 8; ++j) wp[wid][lane * 8 + j] = ps[j];
    }
  }

  trans_store(T, ra, rb, a, e);
  __syncthreads();
  trans_flush(T, oT, c0, r0, R, tid);
  if (pin && tid < 64) {
    pin[(size_t)blockIdx.y * C + c0 + tid] =
        wp[0][tid] + wp[1][tid] + wp[2][tid] + wp[3][tid];
  }
}

// ---------- bf16 [R][C] -> bf16 [C][R] ----------
__global__ void transb(const ushort_t* __restrict__ in,
                       ushort_t* __restrict__ out, int R, int C) {
  __shared__ TransLds T;
  const int c0 = blockIdx.x * 64, r0 = blockIdx.y * 64;
  const int tid = threadIdx.x;
  const int a = tid >> 3, e = tid & 7;
  const int rA = r0 + 2 * a, cB = c0 + e * 8;
  bhalf8 ra = *(const bhalf8*)(in + (size_t)rA * C + cB);
  bhalf8 rb = *(const bhalf8*)(in + (size_t)(rA + 1) * C + cB);
  trans_store(T, ra, rb, a, e);
  __syncthreads();
  trans_flush(T, out, c0, r0, R, tid);
}

// ============ 256x128x32 core: 3-buf, stage-depth-2, counted vmcnt (round-8 schedule) ====
DEV void core(const ushort_t* __restrict__ Ap,
              const ushort_t* __restrict__ Bp,
              size_t ldA, size_t ldB, int nt,
              ushort_t* Lp, int wid, int lane, int wm, int wn,
              floatx4 (&acc)[8][4]) {
  const int lr = lane & 15, kg = lane >> 4;
  const int sslot = ((lane & 3) ^ (((lane & 32) ? 2 : 0) | ((lane & 8) ? 1 : 0))) * 8;
  const ushort_t* gA = Ap + (size_t)(wid * 16 + (lane >> 2)) * ldA + sslot;
  const ushort_t* gB = Bp + (size_t)(wid * 16 + (lane >> 2)) * ldB + sslot;
  const int rslot = ((kg ^ (((lr & 8) ? 2 : 0) | ((lr & 2) ? 1 : 0))) * 8);
  const int aoff = (wm * 128 + lr) * 32 + rslot;
  const int boff = 8192 + (wn * 64 + lr) * 32 + rslot;

  auto stage = [&](int buf, int t) {   // 6 gl16 per wave
    const ushort_t* a = gA + (size_t)t * 32;
    const ushort_t* b = gB + (size_t)t * 32;
    ushort_t* LA = Lp + buf * BUF_SHORTS + wid * 512;
    ushort_t* LB = LA + 8192;
#pragma unroll
    for (int i = 0; i < 4; ++i) gl16(a + (size_t)(i * 64) * ldA, LA + i * 2048);
#pragma unroll
    for (int i = 0; i < 2; ++i) gl16(b + (size_t)(i * 64) * ldB, LB + i * 2048);
  };

  stage(0, 0);
  stage(1, 1);
  int cur = 0, pre = 2;
  for (int t = 0; t < nt; ++t) {
    if (t + 1 < nt) asm volatile("s_waitcnt vmcnt(6)" ::: "memory");
    else            asm volatile("s_waitcnt vmcnt(0)" ::: "memory");
    asm volatile("s_barrier" ::: "memory");
    if (t + 2 < nt) stage(pre, t + 2);
    const ushort_t* aB = Lp + cur * BUF_SHORTS + aoff;
    const ushort_t* bB = Lp + cur * BUF_SHORTS + boff;
    bhalf8 fa[8], fb[4];
#pragma unroll
    for (int m = 0; m < 8; ++m) fa[m] = *(const bhalf8*)(aB + m * 512);
#pragma unroll
    for (int n = 0; n < 4; ++n) fb[n] = *(const bhalf8*)(bB + n * 512);
    asm volatile("s_waitcnt lgkmcnt(0)" ::: "memory");
    __builtin_amdgcn_sched_barrier(0);
    __builtin_amdgcn_s_setprio(1);
#pragma unroll
    for (int m = 0; m < 8; ++m)
#pragma unroll
      for (int n = 0; n < 4; ++n)
        acc[m][n] = __builtin_amdgcn_mfma_f32_16x16x32_bf16(fa[m], fb[n], acc[m][n], 0, 0, 0);
    __builtin_amdgcn_s_setprio(0);
    if (++cur == 3) cur = 0;
    if (++pre == 3) pre = 0;
  }
}

// ---------------- fused NT GEMM: sigmoid(A @ B^T + bias), LDS-repacked epilogue ----------------
// colpart: [NB/256][N] f32 — non-atomic per-block column-sum partials (of p).
// MODE 0: Pout = acts(0/1)   MODE 1: Pout = p, err += (in-p)^2   MODE 2: Pout = p
template <int MODE>
__global__ __launch_bounds__(256, 2)
void gemm_fused256(const ushort_t* __restrict__ Ab,
                   const ushort_t* __restrict__ Bb,
                   int N, int K,
                   const float* __restrict__ bias,
                   const float* __restrict__ rand_h0,
                   ushort_t* __restrict__ Pout,
                   float* __restrict__ colpart,
                   const ushort_t* __restrict__ inbf,
                   float* __restrict__ err_accum) {
  extern __shared__ ushort_t Lsh[];
  const int tid = threadIdx.x;
  const int wid = tid >> 6, lane = tid & 63;
  const int wm = wid >> 1, wn = wid & 1;
  const int lr = lane & 15, kg = lane >> 4;

  const int nwg = gridDim.x * gridDim.y;
  const int id = blockIdx.y * gridDim.x + blockIdx.x;
  const int sid = (id & 7) * (nwg >> 3) + (id >> 3);   // bijective (nwg%8==0)
  const int n0 = (sid % gridDim.x) * 128;
  const int my = sid / gridDim.x;
  const int m0 = my * 256;

  floatx4 acc[8][4] = {};
  core(Ab + (size_t)m0 * K, Bb + (size_t)n0 * K, K, K, K / 32,
       Lsh, wid, lane, wm, wn, acc);

  __syncthreads();                       // core done in all waves; LDS now reusable
  ushort_t* Rt = Lsh;
  float* colp = (float*)(Lsh + LDS_SHORTS);   // 256 floats
  float* ered = colp + 256;
#pragma unroll
  for (int ni = 0; ni < 4; ++ni) {
    const int lcol = wn * 64 + ni * 16 + lr;
    const int col = n0 + lcol;
    const float b = bias[col];
    const float r0 = (MODE == 0) ? rand_h0[col] : 0.0f;
    float cs = 0.0f;
#pragma unroll
    for (int mi = 0; mi < 8; ++mi) {
      const int lrow = wm * 128 + mi * 16 + kg * 4;
#pragma unroll
      for (int r = 0; r < 4; ++r) {
        const float p = sigm(acc[mi][ni][r] + b);
        cs += p;
        ushort_t ov;
        if (MODE == 0) ov = (p >= r0) ? (ushort_t)0x3F80u : (ushort_t)0u;
        else           ov = f2bf(p);
        Rt[(lrow + r) * 132 + lcol] = ov;
      }
    }
    cs += __shfl_xor(cs, 16);
    cs += __shfl_xor(cs, 32);
    if (kg == 0) colp[wm * 128 + lcol] = cs;
  }
  __syncthreads();
  // non-atomic column partial (one row per m-tile)
  if (tid < 128) colpart[(size_t)my * N + n0 + tid] = colp[tid] + colp[128 + tid];
  // ---- coalesced read-out: 16 rows per iteration, bhalf8 per lane ----
  float esum = 0.0f;
  const int c8 = (tid & 15) * 8;
  const int rb = tid >> 4;
#pragma unroll
  for (int it = 0; it < 16; ++it) {
    const int lrow = it * 16 + rb;
    bhalf8 v = *(const bhalf8*)&Rt[lrow * 132 + c8];
    const size_t g = (size_t)(m0 + lrow) * N + n0 + c8;
    *(bhalf8*)&Pout[g] = v;
    if (MODE == 1) {
      bhalf8 iv = *(const bhalf8*)&inbf[g];
#pragma unroll
      for (int j = 0; j < 8; ++j) {
        const float d = bf2f((ushort_t)iv[j]) - bf2f((ushort_t)v[j]);
        esum += d * d;
      }
    }
  }
  if (MODE == 1) {
    esum += __shfl_xor(esum, 1);
    esum += __shfl_xor(esum, 2);
    esum += __shfl_xor(esum, 4);
    esum += __shfl_xor(esum, 8);
    esum += __shfl_xor(esum, 16);
    esum += __shfl_xor(esum, 32);
    if (lane == 0) ered[wid] = esum;
    __syncthreads();
    if (tid == 0) atomicAdd(err_accum, ered[0] + ered[1] + ered[2] + ered[3]);
  }
}

// ---------------- dual NT GEMM: out = A1@B1^T - A2@B2^T (split-K slices) ----------------
// Block mapping: n-panel per XCD (XCD = bid%8 = n-index). B slices (4MB) stay L2-resident
// per XCD; big A panels are shared across XCDs via the die-level L3.
__global__ __launch_bounds__(256, 2)
void gemm_nt_dual(const ushort_t* __restrict__ A1, const ushort_t* __restrict__ B1,
                  const ushort_t* __restrict__ A2, const ushort_t* __restrict__ B2,
                  float* __restrict__ outd) {
  extern __shared__ ushort_t Lsh[];
  const int tid = threadIdx.x;
  const int wid = tid >> 6, lane = tid & 63;
  const int wm = wid >> 1, wn = wid & 1;
  const int lr = lane & 15, kg = lane >> 4;

  const int bid = blockIdx.x;
  const int r = bid & 127;
  const int n0 = (r & 7) * 128;         // 8 n-tiles; XCD = bid%8 = n-index
  const int m0 = (r >> 3) * 256;        // 16 m-tiles (spread across XCDs -> L3 shared)
  const int z  = bid >> 7;              // 4 K-splits
  const size_t kb0 = (size_t)z * (NB / 4);
  constexpr int NT = (NB / 4) / 32;

  floatx4 acc[8][4] = {};
  core(A1 + (size_t)m0 * NB + kb0, B1 + (size_t)n0 * NB + kb0, NB, NB, NT,
       Lsh, wid, lane, wm, wn, acc);
  __syncthreads();                      // all waves done with pass-1 buffers
#pragma unroll
  for (int m = 0; m < 8; ++m)
#pragma unroll
    for (int n = 0; n < 4; ++n)
#pragma unroll
      for (int j = 0; j < 4; ++j) acc[m][n][j] = -acc[m][n][j];
  core(A2 + (size_t)m0 * NB + kb0, B2 + (size_t)n0 * NB + kb0, NB, NB, NT,
       Lsh, wid, lane, wm, wn, acc);
  // acc = P2 - P1 -> write P1 - P2 = -acc
  float* od = outd + (size_t)z * NV * NH;
#pragma unroll
  for (int mi = 0; mi < 8; ++mi) {
    const int rowb = m0 + wm * 128 + mi * 16 + kg * 4;
#pragma unroll
    for (int ni = 0; ni < 4; ++ni) {
      const int col = n0 + wn * 64 + ni * 16 + lr;
#pragma unroll
      for (int r2 = 0; r2 < 4; ++r2)
        od[(size_t)(rowb + r2) * NH + col] = -acc[mi][ni][r2];
    }
  }
}

// ---------------- weight update (sums 4 split-K slices) ----------------
__global__ void wupdate_kernel(const float* __restrict__ W, const float* __restrict__ wm,
                               const float* __restrict__ diff, float* __restrict__ outW) {
  const int i = blockIdx.x * blockDim.x + threadIdx.x;
  constexpr size_t SL = (size_t)NV * NH / 4;
  const floatx4 w = ((const floatx4*)W)[i];
  const floatx4 m = ((const floatx4*)wm)[i];
  const floatx4 a = ((const floatx4*)diff)[i];
  const floatx4 b = ((const floatx4*)diff)[i + SL];
  const floatx4 c = ((const floatx4*)diff)[i + 2 * SL];
  const floatx4 d = ((const floatx4*)diff)[i + 3 * SL];
  floatx4 o;
#pragma unroll
  for (int j = 0; j < 4; ++j)
    o[j] = (w[j] + (m[j] * MOM + (a[j] + b[j]) + (c[j] + d[j])) * LRB) * (1.0f - WD);
  ((floatx4*)outW)[i] = o;
}

// ---------------- bias updates + error: reduce non-atomic partials ----------------
__global__ void biaserr_kernel(const float* __restrict__ vb, const float* __restrict__ vbm,
                               const float* __restrict__ pin, const float* __restrict__ pnvp,
                               const float* __restrict__ hb, const float* __restrict__ hbm,
                               const float* __restrict__ pphp, const float* __restrict__ pnhp,
                               const float* __restrict__ err, float* __restrict__ out) {
  const int i = blockIdx.x * blockDim.x + threadIdx.x;
  if (i < NV) {
    float s_in = 0.0f, s_nvp = 0.0f;
    for (int r = 0; r < NB / 64; ++r) s_in += pin[(size_t)r * NV + i];
    for (int r = 0; r < NB / 256; ++r) s_nvp += pnvp[(size_t)r * NV + i];
    out[1 + (size_t)NV * NH + i] = vb[i] + (vbm[i] * MOM + (s_in - s_nvp)) * LRB;
  }
  if (i < NH) {
    float s_php = 0.0f, s_nhp = 0.0f;
    for (int r = 0; r < NB / 256; ++r) {
      s_php += pphp[(size_t)r * NH + i];
      s_nhp += pnhp[(size_t)r * NH + i];
    }
    out[1 + (size_t)NV * NH + NV + i] = hb[i] + (hbm[i] * MOM + (s_php - s_nhp)) * LRB;
  }
  if (i == 0) out[0] = err[0];
}

extern "C" void kernel_launch(void* const* d_in, const int* in_sizes, int n_in,
                              void* d_out, int out_size, void* d_ws, size_t ws_size,
                              hipStream_t stream) {
  const float* inputs  = (const float*)d_in[0];
  const float* W       = (const float*)d_in[1];
  const float* vb      = (const float*)d_in[2];
  const float* hb      = (const float*)d_in[3];
  const float* wmom    = (const float*)d_in[4];
  const float* vbmom   = (const float*)d_in[5];
  const float* hbmom   = (const float*)d_in[6];
  const float* rand_h0 = (const float*)d_in[7];

  hipFuncSetAttribute((const void*)gemm_fused256<0>, hipFuncAttributeMaxDynamicSharedMemorySize, (int)LDS_BYTES);
  hipFuncSetAttribute((const void*)gemm_fused256<1>, hipFuncAttributeMaxDynamicSharedMemorySize, (int)LDS_BYTES);
  hipFuncSetAttribute((const void*)gemm_fused256<2>, hipFuncAttributeMaxDynamicSharedMemorySize, (int)LDS_BYTES);
  hipFuncSetAttribute((const void*)gemm_nt_dual, hipFuncAttributeMaxDynamicSharedMemorySize, (int)LDS_BYTES);

  char* ws = (char*)d_ws;
  size_t off = 0;
  auto take = [&](size_t b) { size_t r = off; off = (off + b + 1023) & ~(size_t)1023; return r; };
  ushort_t* Wbf   = (ushort_t*)(ws + take((size_t)NV * NH * 2));
  ushort_t* WT    = (ushort_t*)(ws + take((size_t)NV * NH * 2));
  ushort_t* inbf  = (ushort_t*)(ws + take((size_t)NB * NV * 2));  // reused as diff slices
  ushort_t* inT   = (ushort_t*)(ws + take((size_t)NB * NV * 2));
  ushort_t* nvp   = (ushort_t*)(ws + take((size_t)NB * NV * 2));
  ushort_t* nvpT  = (ushort_t*)(ws + take((size_t)NB * NV * 2));
  ushort_t* acts  = (ushort_t*)(ws + take((size_t)NB * NH * 2));  // reused as nhp
  ushort_t* actsT = (ushort_t*)(ws + take((size_t)NB * NH * 2));
  ushort_t* nhpT  = (ushort_t*)(ws + take((size_t)NB * NH * 2));
  float* pin  = (float*)(ws + take((size_t)(NB / 64) * NV * 4));   // 4 MB
  float* pnvp = (float*)(ws + take((size_t)(NB / 256) * NV * 4));  // 1 MB
  float* pphp = (float*)(ws + take((size_t)(NB / 256) * NH * 4));
  float* pnhp = (float*)(ws + take((size_t)(NB / 256) * NH * 4));
  float* errp = (float*)(ws + take(64));

  ushort_t* nhp = acts;          // overlay: acts dead after gemm_fused256<1>
  float* diff   = (float*)inbf;  // overlay: inbf dead after gemm_fused256<1> epilogue

  hipMemsetAsync(errp, 0, 64, stream);   // only remaining atomic accumulator

  // prep: bf16 conversions + transposes (+ non-atomic column partials of inputs)
  prep_cvt_t<<<dim3(NV / 64, NB / 64), 256, 0, stream>>>(inputs, inbf, inT, NB, NV, pin);
  prep_cvt_t<<<dim3(NH / 64, NV / 64), 256, 0, stream>>>(W, Wbf, WT, NV, NH, nullptr);

  // 1) pos hidden: acts = (sigm(inbf @ WT^T + hb) >= rand_h0); php partials
  gemm_fused256<0><<<dim3(NH / 128, NB / 256), 256, LDS_BYTES, stream>>>(
      inbf, WT, NH, NV, hb, rand_h0, acts, pphp, nullptr, nullptr);
  transb<<<dim3(NH / 64, NB / 64), 256, 0, stream>>>(acts, actsT, NB, NH);

  // 2) neg visible: nvp = sigm(acts @ Wbf^T + vb); nvp partials + err
  gemm_fused256<1><<<dim3(NV / 128, NB / 256), 256, LDS_BYTES, stream>>>(
      acts, Wbf, NV, NH, vb, nullptr, nvp, pnvp, inbf, errp);
  transb<<<dim3(NV / 64, NB / 64), 256, 0, stream>>>(nvp, nvpT, NB, NV);

  // 3) neg hidden: nhp = sigm(nvp @ WT^T + hb); nhp partials
  gemm_fused256<2><<<dim3(NH / 128, NB / 256), 256, LDS_BYTES, stream>>>(
      nvp, WT, NH, NV, hb, nullptr, nhp, pnhp, nullptr, nullptr);
  transb<<<dim3(NH / 64, NB / 64), 256, 0, stream>>>(nhp, nhpT, NB, NH);

  // 4) diff slices = inputs^T @ acts - nvp^T @ nhp  (dual-pass, split-K=4)
  gemm_nt_dual<<<dim3(512), 256, LDS_BYTES, stream>>>(inT, actsT, nvpT, nhpT, diff);

  // 5) parameter updates + error (reduces all partial arrays)
  wupdate_kernel<<<dim3((NV * NH / 4) / 256), 256, 0, stream>>>(W, wmom, diff, (float*)d_out + 1);
  biaserr_kernel<<<dim3(16), 256, 0, stream>>>(vb, vbmom, pin, pnvp, hb, hbmom,
                                               pphp, pnhp, errp, (float*)d_out);
}

// Round 12
// 978.200 us; speedup vs baseline: 1.3186x; 1.3186x over previous
//
#include <hip/hip_runtime.h>
#include <hip/hip_bf16.h>

#define DEV __device__ __forceinline__

typedef __attribute__((ext_vector_type(8))) short bhalf8;
typedef __attribute__((ext_vector_type(4))) float floatx4;
typedef unsigned short ushort_t;

constexpr int NB = 16384;   // batch
constexpr int NV = 4096;    // visible
constexpr int NH = 1024;    // hidden
constexpr float MOM = 0.5f;
constexpr float WD  = 1e-4f;
constexpr float LRB = 1e-3f / 16384.0f;

// Tile 256(M) x 128(N) x 32(K); 4 waves, each owns 128x64 (8x4 fragments).
// 3 LDS buffers of 24KB (A 16KB + B 8KB) = 72KB -> 2 blocks/CU.
constexpr int BUF_SHORTS = 12288;            // per buffer
constexpr int LDS_SHORTS = 3 * BUF_SHORTS;   // 36864 shorts = 72KB
constexpr size_t LDS_BYTES = LDS_SHORTS * 2 + 1024 + 64;  // + colp(256f) + ered
// epilogue repack region: [256][132] shorts = 67584 B < 73728 B  (fits)

DEV unsigned short f2bf(float f) {
  unsigned u = __builtin_bit_cast(unsigned, f);
  u += 0x7FFFu + ((u >> 16) & 1u);      // RNE
  return (unsigned short)(u >> 16);
}
DEV float bf2f(unsigned short u) {
  unsigned x = ((unsigned)u) << 16;
  return __builtin_bit_cast(float, x);
}
DEV float sigm(float x) { return 1.0f / (1.0f + __expf(-x)); }

DEV void gl16(const ushort_t* g, ushort_t* l) {
  __builtin_amdgcn_global_load_lds(
      (const __attribute__((address_space(1))) void*)g,
      (__attribute__((address_space(3))) void*)l,
      16, 0, 0);
}

// ================= conflict-free 64x64 bf16 transpose machinery =================
struct TransLds { unsigned U[64 * 33]; };

DEV void trans_store(TransLds& T, const bhalf8& ra, const bhalf8& rb, int a, int e) {
  const unsigned* ua = (const unsigned*)&ra;
  const unsigned* ub = (const unsigned*)&rb;
#pragma unroll
  for (int c2 = 0; c2 < 4; ++c2) {
    unsigned lo = __builtin_amdgcn_perm(ub[c2], ua[c2], 0x05040100u);  // A.lo | B.lo<<16
    unsigned hi = __builtin_amdgcn_perm(ub[c2], ua[c2], 0x07060302u);  // A.hi | B.hi<<16
    T.U[(e * 8 + 2 * c2) * 33 + a] = lo;
    T.U[(e * 8 + 2 * c2 + 1) * 33 + a] = hi;
  }
}

DEV void trans_flush(const TransLds& T, ushort_t* __restrict__ oT,
                     int c0, int r0, int R, int tid) {
  const int g = tid >> 2, f = tid & 3;
  unsigned w[8];
#pragma unroll
  for (int i = 0; i < 8; ++i) w[i] = T.U[g * 33 + f * 8 + i];
  ushort_t* dst = oT + (size_t)(c0 + g) * R + r0 + f * 16;
  *(bhalf8*)dst = *(const bhalf8*)&w[0];
  *(bhalf8*)(dst + 8) = *(const bhalf8*)&w[4];
}

// ---------- f32 [R][C] -> bf16 [R][C] and bf16 [C][R]; non-atomic col partials ----------
__global__ void prep_cvt_t(const float* __restrict__ in,
                           ushort_t* __restrict__ obf,
                           ushort_t* __restrict__ oT, int R, int C,
                           float* __restrict__ pin) {
  __shared__ TransLds T;
  __shared__ float wp[4][64];
  const int c0 = blockIdx.x * 64, r0 = blockIdx.y * 64;
  const int tid = threadIdx.x;
  const int a = tid >> 3, e = tid & 7;
  const int rA = r0 + 2 * a, cB = c0 + e * 8;

  const float* pA = in + (size_t)rA * C + cB;
  const float* pB = pA + C;
  floatx4 a0 = *(const floatx4*)pA, a1 = *(const floatx4*)(pA + 4);
  floatx4 b0 = *(const floatx4*)pB, b1 = *(const floatx4*)(pB + 4);

  bhalf8 ra, rb;
#pragma unroll
  for (int j = 0; j < 4; ++j) {
    ra[j] = (short)f2bf(a0[j]); ra[4 + j] = (short)f2bf(a1[j]);
    rb[j] = (short)f2bf(b0[j]); rb[4 + j] = (short)f2bf(b1[j]);
  }
  *(bhalf8*)(obf + (size_t)rA * C + cB) = ra;
  *(bhalf8*)(obf + (size_t)(rA + 1) * C + cB) = rb;

  if (pin) {
    float ps[8];
#pragma unroll
    for (int j = 0; j < 4; ++j) { ps[j] = a0[j] + b0[j]; ps[4 + j] = a1[j] + b1[j]; }
#pragma unroll
    for (int j = 0; j < 8; ++j) {
      ps[j] += __shfl_xor(ps[j], 8);
      ps[j] += __shfl_xor(ps[j], 16);
      ps[j] += __shfl_xor(ps[j], 32);
    }
    const int wid = tid >> 6, lane = tid & 63;
    if (lane < 8) {
#pragma unroll
      for (int j = 0; j < 8; ++j) wp[wid][lane * 8 + j] = ps[j];
    }
  }

  trans_store(T, ra, rb, a, e);
  __syncthreads();
  trans_flush(T, oT, c0, r0, R, tid);
  if (pin && tid < 64) {
    pin[(size_t)blockIdx.y * C + c0 + tid] =
        wp[0][tid] + wp[1][tid] + wp[2][tid] + wp[3][tid];
  }
}

// ---------- bf16 [R][C] -> bf16 [C][R] ----------
__global__ void transb(const ushort_t* __restrict__ in,
                       ushort_t* __restrict__ out, int R, int C) {
  __shared__ TransLds T;
  const int c0 = blockIdx.x * 64, r0 = blockIdx.y * 64;
  const int tid = threadIdx.x;
  const int a = tid >> 3, e = tid & 7;
  const int rA = r0 + 2 * a, cB = c0 + e * 8;
  bhalf8 ra = *(const bhalf8*)(in + (size_t)rA * C + cB);
  bhalf8 rb = *(const bhalf8*)(in + (size_t)(rA + 1) * C + cB);
  trans_store(T, ra, rb, a, e);
  __syncthreads();
  trans_flush(T, out, c0, r0, R, tid);
}

// ============ 256x128x32 core: 3-buf, stage-depth-2, counted vmcnt (round-8 schedule) ====
DEV void core(const ushort_t* __restrict__ Ap,
              const ushort_t* __restrict__ Bp,
              size_t ldA, size_t ldB, int nt,
              ushort_t* Lp, int wid, int lane, int wm, int wn,
              floatx4 (&acc)[8][4]) {
  const int lr = lane & 15, kg = lane >> 4;
  const int sslot = ((lane & 3) ^ (((lane & 32) ? 2 : 0) | ((lane & 8) ? 1 : 0))) * 8;
  const ushort_t* gA = Ap + (size_t)(wid * 16 + (lane >> 2)) * ldA + sslot;
  const ushort_t* gB = Bp + (size_t)(wid * 16 + (lane >> 2)) * ldB + sslot;
  const int rslot = ((kg ^ (((lr & 8) ? 2 : 0) | ((lr & 2) ? 1 : 0))) * 8);
  const int aoff = (wm * 128 + lr) * 32 + rslot;
  const int boff = 8192 + (wn * 64 + lr) * 32 + rslot;

  auto stage = [&](int buf, int t) {   // 6 gl16 per wave
    const ushort_t* a = gA + (size_t)t * 32;
    const ushort_t* b = gB + (size_t)t * 32;
    ushort_t* LA = Lp + buf * BUF_SHORTS + wid * 512;
    ushort_t* LB = LA + 8192;
#pragma unroll
    for (int i = 0; i < 4; ++i) gl16(a + (size_t)(i * 64) * ldA, LA + i * 2048);
#pragma unroll
    for (int i = 0; i < 2; ++i) gl16(b + (size_t)(i * 64) * ldB, LB + i * 2048);
  };

  stage(0, 0);
  stage(1, 1);
  int cur = 0, pre = 2;
  for (int t = 0; t < nt; ++t) {
    if (t + 1 < nt) asm volatile("s_waitcnt vmcnt(6)" ::: "memory");
    else            asm volatile("s_waitcnt vmcnt(0)" ::: "memory");
    asm volatile("s_barrier" ::: "memory");
    if (t + 2 < nt) stage(pre, t + 2);
    const ushort_t* aB = Lp + cur * BUF_SHORTS + aoff;
    const ushort_t* bB = Lp + cur * BUF_SHORTS + boff;
    bhalf8 fa[8], fb[4];
#pragma unroll
    for (int m = 0; m < 8; ++m) fa[m] = *(const bhalf8*)(aB + m * 512);
#pragma unroll
    for (int n = 0; n < 4; ++n) fb[n] = *(const bhalf8*)(bB + n * 512);
    asm volatile("s_waitcnt lgkmcnt(0)" ::: "memory");
    __builtin_amdgcn_sched_barrier(0);
    __builtin_amdgcn_s_setprio(1);
#pragma unroll
    for (int m = 0; m < 8; ++m)
#pragma unroll
      for (int n = 0; n < 4; ++n)
        acc[m][n] = __builtin_amdgcn_mfma_f32_16x16x32_bf16(fa[m], fb[n], acc[m][n], 0, 0, 0);
    __builtin_amdgcn_s_setprio(0);
    if (++cur == 3) cur = 0;
    if (++pre == 3) pre = 0;
  }
}

// ---------------- fused NT GEMM: sigmoid(A @ B^T + bias), LDS-repacked epilogue ----------------
// colpart: [NB/256][N] f32 — non-atomic per-block column-sum partials (of p).
// MODE 0: Pout = acts(0/1)   MODE 1: Pout = p, err += (in-p)^2   MODE 2: Pout = p
template <int MODE>
__global__ __launch_bounds__(256, 2)
void gemm_fused256(const ushort_t* __restrict__ Ab,
                   const ushort_t* __restrict__ Bb,
                   int N, int K,
                   const float* __restrict__ bias,
                   const float* __restrict__ rand_h0,
                   ushort_t* __restrict__ Pout,
                   float* __restrict__ colpart,
                   const ushort_t* __restrict__ inbf,
                   float* __restrict__ err_accum) {
  extern __shared__ ushort_t Lsh[];
  const int tid = threadIdx.x;
  const int wid = tid >> 6, lane = tid & 63;
  const int wm = wid >> 1, wn = wid & 1;
  const int lr = lane & 15, kg = lane >> 4;

  const int nwg = gridDim.x * gridDim.y;
  const int id = blockIdx.y * gridDim.x + blockIdx.x;
  const int sid = (id & 7) * (nwg >> 3) + (id >> 3);   // bijective (nwg%8==0)
  const int n0 = (sid % gridDim.x) * 128;
  const int my = sid / gridDim.x;
  const int m0 = my * 256;

  floatx4 acc[8][4] = {};
  core(Ab + (size_t)m0 * K, Bb + (size_t)n0 * K, K, K, K / 32,
       Lsh, wid, lane, wm, wn, acc);

  __syncthreads();                       // core done in all waves; LDS now reusable
  ushort_t* Rt = Lsh;
  float* colp = (float*)(Lsh + LDS_SHORTS);   // 256 floats
  float* ered = colp + 256;
#pragma unroll
  for (int ni = 0; ni < 4; ++ni) {
    const int lcol = wn * 64 + ni * 16 + lr;
    const int col = n0 + lcol;
    const float b = bias[col];
    const float r0 = (MODE == 0) ? rand_h0[col] : 0.0f;
    float cs = 0.0f;
#pragma unroll
    for (int mi = 0; mi < 8; ++mi) {
      const int lrow = wm * 128 + mi * 16 + kg * 4;
#pragma unroll
      for (int r = 0; r < 4; ++r) {
        const float p = sigm(acc[mi][ni][r] + b);
        cs += p;
        ushort_t ov;
        if (MODE == 0) ov = (p >= r0) ? (ushort_t)0x3F80u : (ushort_t)0u;
        else           ov = f2bf(p);
        Rt[(lrow + r) * 132 + lcol] = ov;
      }
    }
    cs += __shfl_xor(cs, 16);
    cs += __shfl_xor(cs, 32);
    if (kg == 0) colp[wm * 128 + lcol] = cs;
  }
  __syncthreads();
  // non-atomic column partial (one row per m-tile)
  if (tid < 128) colpart[(size_t)my * N + n0 + tid] = colp[tid] + colp[128 + tid];
  // ---- coalesced read-out: 16 rows per iteration, bhalf8 per lane ----
  float esum = 0.0f;
  const int c8 = (tid & 15) * 8;
  const int rb = tid >> 4;
#pragma unroll
  for (int it = 0; it < 16; ++it) {
    const int lrow = it * 16 + rb;
    bhalf8 v = *(const bhalf8*)&Rt[lrow * 132 + c8];
    const size_t g = (size_t)(m0 + lrow) * N + n0 + c8;
    *(bhalf8*)&Pout[g] = v;
    if (MODE == 1) {
      bhalf8 iv = *(const bhalf8*)&inbf[g];
#pragma unroll
      for (int j = 0; j < 8; ++j) {
        const float d = bf2f((ushort_t)iv[j]) - bf2f((ushort_t)v[j]);
        esum += d * d;
      }
    }
  }
  if (MODE == 1) {
    esum += __shfl_xor(esum, 1);
    esum += __shfl_xor(esum, 2);
    esum += __shfl_xor(esum, 4);
    esum += __shfl_xor(esum, 8);
    esum += __shfl_xor(esum, 16);
    esum += __shfl_xor(esum, 32);
    if (lane == 0) ered[wid] = esum;
    __syncthreads();
    if (tid == 0) atomicAdd(err_accum, ered[0] + ered[1] + ered[2] + ered[3]);
  }
}

// ---------------- dual NT GEMM: out = A1@B1^T - A2@B2^T (split-K slices) ----------------
// Round-8 mapping: m-panel per XCD (XCD = bid%8 = m-index%8) — A slices stay L2-resident.
__global__ __launch_bounds__(256, 2)
void gemm_nt_dual(const ushort_t* __restrict__ A1, const ushort_t* __restrict__ B1,
                  const ushort_t* __restrict__ A2, const ushort_t* __restrict__ B2,
                  float* __restrict__ outd) {
  extern __shared__ ushort_t Lsh[];
  const int tid = threadIdx.x;
  const int wid = tid >> 6, lane = tid & 63;
  const int wm = wid >> 1, wn = wid & 1;
  const int lr = lane & 15, kg = lane >> 4;

  const int bid = blockIdx.x;
  const int r = bid & 127;
  const int m0 = (r & 15) * 256;        // 16 m-tiles (same m -> same XCD)
  const int n0 = (r >> 4) * 128;        // 8 n-tiles
  const int z  = bid >> 7;              // 4 K-splits
  const size_t kb0 = (size_t)z * (NB / 4);
  constexpr int NT = (NB / 4) / 32;

  floatx4 acc[8][4] = {};
  core(A1 + (size_t)m0 * NB + kb0, B1 + (size_t)n0 * NB + kb0, NB, NB, NT,
       Lsh, wid, lane, wm, wn, acc);
  __syncthreads();                      // all waves done with pass-1 buffers
#pragma unroll
  for (int m = 0; m < 8; ++m)
#pragma unroll
    for (int n = 0; n < 4; ++n)
#pragma unroll
      for (int j = 0; j < 4; ++j) acc[m][n][j] = -acc[m][n][j];
  core(A2 + (size_t)m0 * NB + kb0, B2 + (size_t)n0 * NB + kb0, NB, NB, NT,
       Lsh, wid, lane, wm, wn, acc);
  // acc = P2 - P1 -> write P1 - P2 = -acc
  float* od = outd + (size_t)z * NV * NH;
#pragma unroll
  for (int mi = 0; mi < 8; ++mi) {
    const int rowb = m0 + wm * 128 + mi * 16 + kg * 4;
#pragma unroll
    for (int ni = 0; ni < 4; ++ni) {
      const int col = n0 + wn * 64 + ni * 16 + lr;
#pragma unroll
      for (int r2 = 0; r2 < 4; ++r2)
        od[(size_t)(rowb + r2) * NH + col] = -acc[mi][ni][r2];
    }
  }
}

// ---------------- weight update (sums 4 split-K slices) ----------------
__global__ void wupdate_kernel(const float* __restrict__ W, const float* __restrict__ wm,
                               const float* __restrict__ diff, float* __restrict__ outW) {
  const int i = blockIdx.x * blockDim.x + threadIdx.x;
  constexpr size_t SL = (size_t)NV * NH / 4;
  const floatx4 w = ((const floatx4*)W)[i];
  const floatx4 m = ((const floatx4*)wm)[i];
  const floatx4 a = ((const floatx4*)diff)[i];
  const floatx4 b = ((const floatx4*)diff)[i + SL];
  const floatx4 c = ((const floatx4*)diff)[i + 2 * SL];
  const floatx4 d = ((const floatx4*)diff)[i + 3 * SL];
  floatx4 o;
#pragma unroll
  for (int j = 0; j < 4; ++j)
    o[j] = (w[j] + (m[j] * MOM + (a[j] + b[j]) + (c[j] + d[j])) * LRB) * (1.0f - WD);
  ((floatx4*)outW)[i] = o;
}

// ---------------- bias updates + error: reduce non-atomic partials ----------------
__global__ void biaserr_kernel(const float* __restrict__ vb, const float* __restrict__ vbm,
                               const float* __restrict__ pin, const float* __restrict__ pnvp,
                               const float* __restrict__ hb, const float* __restrict__ hbm,
                               const float* __restrict__ pphp, const float* __restrict__ pnhp,
                               const float* __restrict__ err, float* __restrict__ out) {
  const int i = blockIdx.x * blockDim.x + threadIdx.x;
  if (i < NV) {
    float s_in = 0.0f, s_nvp = 0.0f;
    for (int r = 0; r < NB / 64; ++r) s_in += pin[(size_t)r * NV + i];
    for (int r = 0; r < NB / 256; ++r) s_nvp += pnvp[(size_t)r * NV + i];
    out[1 + (size_t)NV * NH + i] = vb[i] + (vbm[i] * MOM + (s_in - s_nvp)) * LRB;
  }
  if (i < NH) {
    float s_php = 0.0f, s_nhp = 0.0f;
    for (int r = 0; r < NB / 256; ++r) {
      s_php += pphp[(size_t)r * NH + i];
      s_nhp += pnhp[(size_t)r * NH + i];
    }
    out[1 + (size_t)NV * NH + NV + i] = hb[i] + (hbm[i] * MOM + (s_php - s_nhp)) * LRB;
  }
  if (i == 0) out[0] = err[0];
}

extern "C" void kernel_launch(void* const* d_in, const int* in_sizes, int n_in,
                              void* d_out, int out_size, void* d_ws, size_t ws_size,
                              hipStream_t stream) {
  const float* inputs  = (const float*)d_in[0];
  const float* W       = (const float*)d_in[1];
  const float* vb      = (const float*)d_in[2];
  const float* hb      = (const float*)d_in[3];
  const float* wmom    = (const float*)d_in[4];
  const float* vbmom   = (const float*)d_in[5];
  const float* hbmom   = (const float*)d_in[6];
  const float* rand_h0 = (const float*)d_in[7];

  hipFuncSetAttribute((const void*)gemm_fused256<0>, hipFuncAttributeMaxDynamicSharedMemorySize, (int)LDS_BYTES);
  hipFuncSetAttribute((const void*)gemm_fused256<1>, hipFuncAttributeMaxDynamicSharedMemorySize, (int)LDS_BYTES);
  hipFuncSetAttribute((const void*)gemm_fused256<2>, hipFuncAttributeMaxDynamicSharedMemorySize, (int)LDS_BYTES);
  hipFuncSetAttribute((const void*)gemm_nt_dual, hipFuncAttributeMaxDynamicSharedMemorySize, (int)LDS_BYTES);

  char* ws = (char*)d_ws;
  size_t off = 0;
  auto take = [&](size_t b) { size_t r = off; off = (off + b + 1023) & ~(size_t)1023; return r; };
  ushort_t* Wbf   = (ushort_t*)(ws + take((size_t)NV * NH * 2));
  ushort_t* WT    = (ushort_t*)(ws + take((size_t)NV * NH * 2));
  ushort_t* inbf  = (ushort_t*)(ws + take((size_t)NB * NV * 2));  // reused as diff slices
  ushort_t* inT   = (ushort_t*)(ws + take((size_t)NB * NV * 2));
  ushort_t* nvp   = (ushort_t*)(ws + take((size_t)NB * NV * 2));
  ushort_t* nvpT  = (ushort_t*)(ws + take((size_t)NB * NV * 2));
  ushort_t* acts  = (ushort_t*)(ws + take((size_t)NB * NH * 2));  // reused as nhp
  ushort_t* actsT = (ushort_t*)(ws + take((size_t)NB * NH * 2));
  ushort_t* nhpT  = (ushort_t*)(ws + take((size_t)NB * NH * 2));
  float* pin  = (float*)(ws + take((size_t)(NB / 64) * NV * 4));   // 4 MB
  float* pnvp = (float*)(ws + take((size_t)(NB / 256) * NV * 4));  // 1 MB
  float* pphp = (float*)(ws + take((size_t)(NB / 256) * NH * 4));
  float* pnhp = (float*)(ws + take((size_t)(NB / 256) * NH * 4));
  float* errp = (float*)(ws + take(64));

  ushort_t* nhp = acts;          // overlay: acts dead after gemm_fused256<1>
  float* diff   = (float*)inbf;  // overlay: inbf dead after gemm_fused256<1> epilogue

  hipMemsetAsync(errp, 0, 64, stream);   // only remaining atomic accumulator

  // prep: bf16 conversions + transposes (+ non-atomic column partials of inputs)
  prep_cvt_t<<<dim3(NV / 64, NB / 64), 256, 0, stream>>>(inputs, inbf, inT, NB, NV, pin);
  prep_cvt_t<<<dim3(NH / 64, NV / 64), 256, 0, stream>>>(W, Wbf, WT, NV, NH, nullptr);

  // 1) pos hidden: acts = (sigm(inbf @ WT^T + hb) >= rand_h0); php partials
  gemm_fused256<0><<<dim3(NH / 128, NB / 256), 256, LDS_BYTES, stream>>>(
      inbf, WT, NH, NV, hb, rand_h0, acts, pphp, nullptr, nullptr);
  transb<<<dim3(NH / 64, NB / 64), 256, 0, stream>>>(acts, actsT, NB, NH);

  // 2) neg visible: nvp = sigm(acts @ Wbf^T + vb); nvp partials + err
  gemm_fused256<1><<<dim3(NV / 128, NB / 256), 256, LDS_BYTES, stream>>>(
      acts, Wbf, NV, NH, vb, nullptr, nvp, pnvp, inbf, errp);
  transb<<<dim3(NV / 64, NB / 64), 256, 0, stream>>>(nvp, nvpT, NB, NV);

  // 3) neg hidden: nhp = sigm(nvp @ WT^T + hb); nhp partials
  gemm_fused256<2><<<dim3(NH / 128, NB / 256), 256, LDS_BYTES, stream>>>(
      nvp, WT, NH, NV, hb, nullptr, nhp, pnhp, nullptr, nullptr);
  transb<<<dim3(NH / 64, NB / 64), 256, 0, stream>>>(nhp, nhpT, NB, NH);

  // 4) diff slices = inputs^T @ acts - nvp^T @ nhp  (dual-pass, split-K=4)
  gemm_nt_dual<<<dim3(512), 256, LDS_BYTES, stream>>>(inT, actsT, nvpT, nhpT, diff);

  // 5) parameter updates + error (reduces all partial arrays)
  wupdate_kernel<<<dim3((NV * NH / 4) / 256), 256, 0, stream>>>(W, wmom, diff, (float*)d_out + 1);
  biaserr_kernel<<<dim3(16), 256, 0, stream>>>(vb, vbmom, pin, pnvp, hb, hbmom,
                                               pphp, pnhp, errp, (float*)d_out);
}